// Round 1
// baseline (355.663 us; speedup 1.0000x reference)
//
#include <hip/hip_runtime.h>

// Problem constants (from reference)
#define B_      8
#define C_OUT_  64
#define GROUPS_ 4
#define NK_     7
#define C_IN_   1792          // GROUPS_ * C_OUT_ * NK_
#define L_      4096
#define NCH     28            // GROUPS_ * NK_ channels feeding one c_out

// Tiling
#define T_TILE  256
#define HALO    16            // shifts are in [-15, 15]
#define ROW     (T_TILE + 2 * HALO)   // 288 floats per staged channel row

// shift = REAL_PAD[idx % 7] = 15 - 5*(idx % 7)
// dst t reads src t - shift -> LDS index = tid + HALO - (15 - 5m) = tid + 1 + 5m

__global__ __launch_bounds__(256)
void addshift_fused_kernel(const float* __restrict__ x,
                           const int*   __restrict__ s1,
                           const int*   __restrict__ s2,
                           const int*   __restrict__ s3,
                           float*       __restrict__ out)
{
    __shared__ float lx[NCH * ROW];   // 28 * 288 * 4 B = 31.5 KB

    const int tid  = threadIdx.x;
    const int blk  = blockIdx.x;
    const int tile = blk & (L_ / T_TILE - 1);   // 16 tiles along L
    const int co   = (blk >> 4) & (C_OUT_ - 1);
    const int b    = blk >> 10;                 // 8 batches
    const int t0   = tile * T_TILE;

    const int base_b = b * (C_IN_ * L_);        // fits in int (max ~51M)

    // ---- Stage 28 channel rows (with halo, zero-filled OOB) via float4 ----
    // Total: NCH * ROW/4 = 28 * 72 = 2016 float4 loads per block.
    for (int i = tid; i < NCH * (ROW / 4); i += 256) {
        const int cl = i / (ROW / 4);           // 0..27
        const int j  = i - cl * (ROW / 4);      // 0..71
        const int g  = cl / NK_;
        const int k  = cl - g * NK_;
        const int ch = g * (C_OUT_ * NK_) + co * NK_ + k;
        const int e  = t0 - HALO + j * 4;       // 64B-aligned element index
        const float* src = x + base_b + ch * L_ + e;
        float4 v;
        if (e >= 0 && e + 4 <= L_) {
            v = *(const float4*)src;            // aligned fast path
        } else {                                // first/last tile edges only
            v.x = (e + 0 >= 0 && e + 0 < L_) ? src[0] : 0.f;
            v.y = (e + 1 >= 0 && e + 1 < L_) ? src[1] : 0.f;
            v.z = (e + 2 >= 0 && e + 2 < L_) ? src[2] : 0.f;
            v.w = (e + 3 >= 0 && e + 3 < L_) ? src[3] : 0.f;
        }
        *(float4*)&lx[cl * ROW + j * 4] = v;
    }
    __syncthreads();

    // ---- Accumulate 3 outputs; shifts are block-uniform (SALU/scalar) ----
    float acc1 = 0.f, acc2 = 0.f, acc3 = 0.f;
#pragma unroll
    for (int g = 0; g < GROUPS_; ++g) {
#pragma unroll
        for (int k = 0; k < NK_; ++k) {
            const int cl = g * NK_ + k;
            const int ch = g * (C_OUT_ * NK_) + co * NK_ + k;
            const int m1 = s1[ch] % NK_;        // scalar load + SALU magic-div
            const int m2 = s2[ch] % NK_;
            const int m3 = s3[ch] % NK_;
            const float* row = &lx[cl * ROW + tid + 1];
            acc1 += row[5 * m1];                // conflict-free ds_read_b32
            acc2 += row[5 * m2];
            acc3 += row[5 * m3];
        }
    }

    const int opos = (b * C_OUT_ + co) * L_ + t0 + tid;
    out[opos]                     = acc1;
    out[B_ * C_OUT_ * L_ + opos]  = acc2;
    out[2 * B_ * C_OUT_ * L_ + opos] = acc3;
}

extern "C" void kernel_launch(void* const* d_in, const int* in_sizes, int n_in,
                              void* d_out, int out_size, void* d_ws, size_t ws_size,
                              hipStream_t stream) {
    const float* x  = (const float*)d_in[0];
    const int*   s1 = (const int*)d_in[1];
    const int*   s2 = (const int*)d_in[2];
    const int*   s3 = (const int*)d_in[3];
    float* out = (float*)d_out;

    const int n_blocks = B_ * C_OUT_ * (L_ / T_TILE);   // 8192
    addshift_fused_kernel<<<dim3(n_blocks), dim3(256), 0, stream>>>(x, s1, s2, s3, out);
}

// Round 2
// 322.671 us; speedup vs baseline: 1.1022x; 1.1022x over previous
//
#include <hip/hip_runtime.h>

// Problem constants (from reference)
#define B_      8
#define C_OUT_  64
#define GROUPS_ 4
#define NK_     7
#define C_IN_   1792          // GROUPS_ * C_OUT_ * NK_
#define L_      4096
#define NCH     28            // GROUPS_ * NK_ channels feeding one c_out

// Tiling
#define T_TILE  256
#define HALO    16            // shifts are in [-15, 15]
#define ROW     (T_TILE + 2 * HALO)     // 288 floats per staged channel row
#define NGRAN   (NCH * (ROW / 4))       // 2016 float4 granules of real data
#define NGRAN_P 2048                    // padded to 8*256 -> LDS = exactly 32 KB

// shift = REAL_PAD[idx % 7] = 15 - 5*(idx % 7)
// dst t reads src t - shift -> LDS index = tid + HALO - (15 - 5m) = tid + 1 + 5m

__global__ __launch_bounds__(256, 5)
void addshift_fused_kernel(const float* __restrict__ x,
                           const int*   __restrict__ s1,
                           const int*   __restrict__ s2,
                           const int*   __restrict__ s3,
                           float*       __restrict__ out)
{
    __shared__ float lx[NGRAN_P * 4];   // 32 KB -> 5 blocks/CU (LDS-limited)

    const int tid  = threadIdx.x;
    const int blk  = blockIdx.x;
    const int tile = blk & (L_ / T_TILE - 1);   // 16 tiles along L
    const int co   = (blk >> 4) & (C_OUT_ - 1);
    const int b    = blk >> 10;                 // 8 batches
    const int t0   = tile * T_TILE;

    const int base_b = b * (C_IN_ * L_);        // max ~51.4M, fits int

    // ---- Stage 28 channel rows: fully unrolled, batched loads ----
    // Phase A: compute 8 addresses + issue 8 unconditional float4 loads
    // (max in-flight bytes per wave), Phase B: zero-fix + ds_write_b128.
    float4 v[8];
    bool   ok[8];
#pragma unroll
    for (int it = 0; it < 8; ++it) {
        const int gi  = it * 256 + tid;                    // 0..2047
        const int gic = gi > (NGRAN - 1) ? (NGRAN - 1) : gi; // clamp tail -> valid addr
        const int cl  = gic / (ROW / 4);                   // 0..27 (magic div)
        const int j   = gic - cl * (ROW / 4);              // 0..71
        const int g   = cl / NK_;
        const int k   = cl - g * NK_;
        const int ch  = g * (C_OUT_ * NK_) + co * NK_ + k;
        const int e   = t0 - HALO + j * 4;                 // multiple of 4
        // granule is always fully inside or fully outside [0, L)
        ok[it] = (e >= 0) && (e <= L_ - 4);
        const int ec  = e < 0 ? 0 : (e > L_ - 4 ? L_ - 4 : e);
        v[it] = *(const float4*)(x + base_b + ch * L_ + ec);
    }
#pragma unroll
    for (int it = 0; it < 8; ++it) {
        if (!ok[it]) v[it] = make_float4(0.f, 0.f, 0.f, 0.f);
        *(float4*)&lx[(it * 256 + tid) * 4] = v[it];
    }
    __syncthreads();

    // ---- Accumulate 3 outputs; shifts are block-uniform (s_load + SALU) ----
    float acc1 = 0.f, acc2 = 0.f, acc3 = 0.f;
    const float* lbase = &lx[tid + 1];
#pragma unroll
    for (int g = 0; g < GROUPS_; ++g) {
#pragma unroll
        for (int k = 0; k < NK_; ++k) {
            const int cl = g * NK_ + k;
            const int ch = g * (C_OUT_ * NK_) + co * NK_ + k;
            const int m1 = s1[ch] % NK_;        // uniform -> SALU magic-div
            const int m2 = s2[ch] % NK_;
            const int m3 = s3[ch] % NK_;
            const float* row = lbase + cl * ROW;
            acc1 += row[5 * m1];                // conflict-free ds_read_b32
            acc2 += row[5 * m2];
            acc3 += row[5 * m3];
        }
    }

    const int opos = (b * C_OUT_ + co) * L_ + t0 + tid;
    out[opos]                        = acc1;
    out[B_ * C_OUT_ * L_ + opos]     = acc2;
    out[2 * B_ * C_OUT_ * L_ + opos] = acc3;
}

extern "C" void kernel_launch(void* const* d_in, const int* in_sizes, int n_in,
                              void* d_out, int out_size, void* d_ws, size_t ws_size,
                              hipStream_t stream) {
    const float* x  = (const float*)d_in[0];
    const int*   s1 = (const int*)d_in[1];
    const int*   s2 = (const int*)d_in[2];
    const int*   s3 = (const int*)d_in[3];
    float* out = (float*)d_out;

    const int n_blocks = B_ * C_OUT_ * (L_ / T_TILE);   // 8192
    addshift_fused_kernel<<<dim3(n_blocks), dim3(256), 0, stream>>>(x, s1, s2, s3, out);
}